// Round 1
// baseline (108.279 us; speedup 1.0000x reference)
//
#include <hip/hip_runtime.h>
#include <math.h>
#include <float.h>

#define EPS 1e-6f
#define THRESHOLD 0.5f

// One wave (64 lanes) per point. 4800 points total.
// points: (16,10,30,2) fp32, polys: (16,16,200,2) fp32, out: (16,10) fp32.
__global__ __launch_bounds__(64) void offroad_kernel(
    const float* __restrict__ points,
    const float* __restrict__ polys,
    float* __restrict__ out)
{
    const int i   = blockIdx.x;        // global point index 0..4799
    const int b   = i / 300;           // batch
    const int rem = i % 300;
    const int a   = rem / 30;          // agent
    const int lane = threadIdx.x;      // 0..63

    const float2 pt = *(const float2*)(points + (size_t)i * 2);
    const float px = pt.x, py = pt.y;

    float min_dsq = FLT_MAX;
    int crossings = 0;

    const float2* polyb = (const float2*)polys + (size_t)b * 16 * 200;

    for (int m = 0; m < 16; ++m) {
        const float2* poly = polyb + m * 200;
        for (int v = lane; v < 199; v += 64) {
            const float2 s = poly[v];
            const float2 e = poly[v + 1];

            // ---- point-to-segment squared distance ----
            const float evx = e.x - s.x, evy = e.y - s.y;
            const float v1x = px - s.x, v1y = py - s.y;
            const float dot = v1x * evx + v1y * evy;
            const float esq = evx * evx + evy * evy;
            float t = dot / (esq + EPS);
            t = fminf(fmaxf(t, 0.0f), 1.0f);
            const float cx = evx * t + s.x;
            const float cy = evy * t + s.y;
            const float dx = px - cx, dy = py - cy;
            const float dsq = dx * dx + dy * dy;
            min_dsq = fminf(min_dsq, dsq);

            // ---- even-odd crossing test (replicate reference fp32 ops exactly) ----
            const bool cond_y = ((s.y <= py) & (py < e.y)) | ((e.y <= py) & (py < s.y));
            const float slope = (e.y - s.y) / (e.x - s.x + EPS);
            const float ix = s.x + (py - s.y) / (slope + EPS);
            const bool is_left = ix > px;
            crossings += (cond_y & is_left) ? 1 : 0;
        }
    }

    // ---- wave-64 butterfly reduction: min(dsq), sum(crossings) ----
    for (int off = 32; off > 0; off >>= 1) {
        min_dsq  = fminf(min_dsq, __shfl_xor(min_dsq, off));
        crossings += __shfl_xor(crossings, off);
    }

    if (lane == 0) {
        float md = sqrtf(fmaxf(min_dsq, EPS));
        if (crossings & 1) md = -md;
        const float val = fmaxf(md + THRESHOLD, 0.0f);
        atomicAdd(out + (b * 10 + a), val);
    }
}

extern "C" void kernel_launch(void* const* d_in, const int* in_sizes, int n_in,
                              void* d_out, int out_size, void* d_ws, size_t ws_size,
                              hipStream_t stream) {
    const float* points = (const float*)d_in[0];   // (16,10,30,2)
    const float* polys  = (const float*)d_in[1];   // (16,16,200,2)
    float* out = (float*)d_out;                    // (16,10)

    // d_out is poisoned 0xAA before every timed launch — zero it (capture-legal).
    hipMemsetAsync(d_out, 0, (size_t)out_size * sizeof(float), stream);

    offroad_kernel<<<4800, 64, 0, stream>>>(points, polys, out);
}

// Round 2
// 83.788 us; speedup vs baseline: 1.2923x; 1.2923x over previous
//
#include <hip/hip_runtime.h>
#include <math.h>
#include <float.h>

#define EPS 1e-6f
#define THRESHOLD 0.5f

#define NB 16
#define NPOLY 16
#define NVERT 200
#define NSEG_PER_POLY 199
#define NSEG (NPOLY * NSEG_PER_POLY)   // 3184 segments per batch
#define NPOINTS 4800                   // 16*10*30

// ---------------------------------------------------------------------------
// Pass 1: per-(batch, segment) precompute. Hoists the two segment-only
// divisions (1/(esq+EPS) and slope) out of the 15.3M-eval hot loop.
// Entry layout (2x float4, 32 B): [sx, sy, evx, evy] [inv_esq, slope_eps, ey, 0]
// Exactness notes:
//   evx/evy   = e-s, identical op to reference ev.
//   slope_eps = evy/(evx+EPS) + EPS, identical rounding order to reference
//               (ey-sy), (ex-sx)+EPS, div, +EPS.
//   inv_esq feeds the distance path only (ulp drift tolerated).
// Also zeroes out[] (d_out is poisoned 0xAA before every launch).
// ---------------------------------------------------------------------------
__global__ __launch_bounds__(256) void precompute_kernel(
    const float* __restrict__ polys,
    float4* __restrict__ table,
    float* __restrict__ out)
{
    const int idx = blockIdx.x * 256 + threadIdx.x;
    if (idx < 160) out[idx] = 0.0f;
    if (idx >= NB * NSEG) return;

    const int b = idx / NSEG;
    const int s = idx % NSEG;
    const int m = s / NSEG_PER_POLY;
    const int v = s % NSEG_PER_POLY;

    const float2* poly = (const float2*)polys + ((size_t)(b * NPOLY + m) * NVERT);
    const float2 S = poly[v];
    const float2 E = poly[v + 1];

    const float evx = E.x - S.x;
    const float evy = E.y - S.y;
    const float esq = evx * evx + evy * evy;
    const float inv_esq = 1.0f / (esq + EPS);         // distance path: approx-tolerant
    const float slope = evy / (evx + EPS);            // exact IEEE div, ref rounding order
    const float slope_eps = slope + EPS;

    table[idx * 2]     = make_float4(S.x, S.y, evx, evy);
    table[idx * 2 + 1] = make_float4(inv_esq, slope_eps, E.y, 0.0f);
}

// ---------------------------------------------------------------------------
// Pass 2: one wave per point (4 waves / block). Each lane strides the flat
// 3184-segment table; single IEEE division per eval (crossing test — must be
// bit-exact vs numpy so the inside-parity never flips).
// ---------------------------------------------------------------------------
__global__ __launch_bounds__(256) void offroad_kernel(
    const float* __restrict__ points,
    const float4* __restrict__ table,
    float* __restrict__ out)
{
    const int wave = threadIdx.x >> 6;
    const int lane = threadIdx.x & 63;
    const int i = blockIdx.x * 4 + wave;   // point index 0..4799
    const int b   = i / 300;
    const int a   = (i % 300) / 30;

    const float2 pt = *(const float2*)(points + (size_t)i * 2);
    const float px = pt.x, py = pt.y;

    const float4* tb = table + (size_t)b * NSEG * 2;

    float min_dsq = FLT_MAX;
    int crossings = 0;

    #pragma unroll 2
    for (int s = lane; s < NSEG; s += 64) {
        const float4 p0 = tb[s * 2];
        const float4 p1 = tb[s * 2 + 1];
        const float sx = p0.x, sy = p0.y, evx = p0.z, evy = p0.w;
        const float inv_esq = p1.x, slope_eps = p1.y, ey = p1.z;

        // ---- point-to-segment squared distance (approx-tolerant path) ----
        const float v1x = px - sx;
        const float v1y = py - sy;
        const float dot = v1x * evx + v1y * evy;
        float t = dot * inv_esq;
        t = fminf(fmaxf(t, 0.0f), 1.0f);
        const float dx = px - (evx * t + sx);
        const float dy = py - (evy * t + sy);
        const float dsq = dx * dx + dy * dy;
        min_dsq = fminf(min_dsq, dsq);

        // ---- even-odd crossing (bit-exact path) ----
        const bool cond_y = ((sy <= py) & (py < ey)) | ((ey <= py) & (py < sy));
        const float ix = sx + v1y / slope_eps;   // exact IEEE div, same ops as ref
        crossings += (cond_y & (ix > px)) ? 1 : 0;
    }

    // ---- wave-64 butterfly reduction ----
    for (int off = 32; off > 0; off >>= 1) {
        min_dsq   = fminf(min_dsq, __shfl_xor(min_dsq, off));
        crossings += __shfl_xor(crossings, off);
    }

    if (lane == 0) {
        float md = sqrtf(fmaxf(min_dsq, EPS));
        if (crossings & 1) md = -md;
        const float val = fmaxf(md + THRESHOLD, 0.0f);
        atomicAdd(out + (b * 10 + a), val);
    }
}

extern "C" void kernel_launch(void* const* d_in, const int* in_sizes, int n_in,
                              void* d_out, int out_size, void* d_ws, size_t ws_size,
                              hipStream_t stream) {
    const float* points = (const float*)d_in[0];   // (16,10,30,2)
    const float* polys  = (const float*)d_in[1];   // (16,16,200,2)
    float* out = (float*)d_out;                    // (16,10)
    float4* table = (float4*)d_ws;                 // 16*3184*32 B = 1.63 MB

    const int n_entries = NB * NSEG;               // 50944
    precompute_kernel<<<(n_entries + 255) / 256, 256, 0, stream>>>(polys, table, out);
    offroad_kernel<<<NPOINTS / 4, 256, 0, stream>>>(points, table, out);
}